// Round 5
// baseline (202.690 us; speedup 1.0000x reference)
//
#include <hip/hip_runtime.h>
#include <cstddef>
#include <cstdint>

// Problem constants (fixed by reference file)
#define B_    256
#define V_    128000
#define T_    16
#define TOPK_ 100
#define TPB   1024
#define CAP   4096
#define NF4   (V_ / 4)      // 32000 float4 per row
#define NHIST 4096          // fallback histogram bins over [0,1)
#define NB    1024          // selection histogram bins over [lo,1)
#define BINCAP 256          // in-bin candidate cap for exact tie handling
#define T0    0.996f        // speculative threshold (~512 candidates/row expected)

__global__ void zero_out_kernel(float* o) {
    o[0] = 0.f; o[1] = 0.f; o[2] = 0.f;
}

// ---------------------------------------------------------------------------
// One block per row (256 blocks x 1024 threads, 1 block/CU, 16 waves).
// Streaming scan uses an explicit double-buffered register pipeline:
// two 8-deep float4 batches; the next batch's loads are issued BEFORE the
// current batch is processed, so >=8 loads/wave stay in flight through all
// compute (no vmcnt(0) drain between batches). Selection: exact top-100 sum
// via 1024-bin histogram (~6 barriers) with exact in-bin tie handling;
// proven full-row NHIST fallback if speculation fails. No ws, no fences.
//
// Per-thread index map: k = 0..31, idx = k*TPB + tid (tail k=31 covers
// only tid < 256 since NF4 = 31*1024 + 256).
// Pipeline: load A(k=0..7) | load B(k=8..15) | proc A | load A'(k=16..23)
//           | proc B | load B'(k=24..30, 7 deep) | proc A' | proc B' | tail.
// ---------------------------------------------------------------------------
__global__ __launch_bounds__(TPB) void row_kernel(
        const float* __restrict__ sparse,
        const int*   __restrict__ tids,
        float*       __restrict__ out) {
    __shared__ float    s_cand[CAP];        // 16 KB
    __shared__ unsigned s_hist[NHIST];      // 16 KB (fallback all, select first NB)
    __shared__ unsigned s_chunk[NB / 4];    // 1 KB
    __shared__ float    s_bin[BINCAP];      // 1 KB
    __shared__ float    s_wred[16];
    __shared__ int      s_ids[T_];
    __shared__ int      s_cnt, s_bq, s_bstar, s_above;

    const int row = blockIdx.x;
    const int tid = threadIdx.x;
    const float* __restrict__ rp = sparse + (size_t)row * V_;

    if (tid < T_) s_ids[tid] = tids[row * T_ + tid];
    if (tid == 0) { s_cnt = 0; s_bq = 0; }
    __syncthreads();

    // ---- target loss + margin loss (lanes 0..15 of wave 0) ----
    if (tid < T_) {
        float x  = rp[s_ids[tid]];
        float tl = -logf(x + 1e-8f);
        float ml = fmaxf(1.0f - x, 0.0f);
        #pragma unroll
        for (int off = 8; off > 0; off >>= 1) {
            tl += __shfl_down(tl, off);
            ml += __shfl_down(ml, off);
        }
        if (tid == 0) {
            atomicAdd(out + 0, tl * (1.0f / (B_ * T_)));
            atomicAdd(out + 1, ml * (1.0f / (B_ * T_)));
        }
    }

    const float4* __restrict__ rp4 = (const float4*)rp;

    auto proc = [&](float4 v, int i4) {
        float mx = fmaxf(fmaxf(v.x, v.y), fmaxf(v.z, v.w));
        if (mx >= T0) {                       // taken ~1.6% of the time
            int col = i4 << 2;
            float xs[4] = {v.x, v.y, v.z, v.w};
            #pragma unroll
            for (int c = 0; c < 4; ++c) {
                float x = xs[c];
                if (x >= T0) {
                    int cc = col + c;
                    bool is_t = false;
                    #pragma unroll
                    for (int j = 0; j < T_; ++j) is_t |= (cc == s_ids[j]);
                    if (!is_t) {
                        int k = atomicAdd(&s_cnt, 1);
                        if (k < CAP) s_cand[k] = x;
                    }
                }
            }
        }
    };

    {
        float4 a[8], b[8];

        // prologue: fill both buffers (16 loads in flight)
        #pragma unroll
        for (int k = 0; k < 8; ++k) a[k] = rp4[k * TPB + tid];
        #pragma unroll
        for (int k = 0; k < 8; ++k) b[k] = rp4[(8 + k) * TPB + tid];

        // proc A (k=0..7) while B (8..15) is in flight
        #pragma unroll
        for (int k = 0; k < 8; ++k) proc(a[k], k * TPB + tid);

        // refill A with k=16..23 before touching B
        #pragma unroll
        for (int k = 0; k < 8; ++k) a[k] = rp4[(16 + k) * TPB + tid];

        // proc B (k=8..15) while A' (16..23) is in flight
        #pragma unroll
        for (int k = 0; k < 8; ++k) proc(b[k], (8 + k) * TPB + tid);

        // refill B with k=24..30 (7 deep) before touching A'
        #pragma unroll
        for (int k = 0; k < 7; ++k) b[k] = rp4[(24 + k) * TPB + tid];

        // proc A' (16..23) while B' (24..30) is in flight
        #pragma unroll
        for (int k = 0; k < 8; ++k) proc(a[k], (16 + k) * TPB + tid);

        // proc B' (24..30)
        #pragma unroll
        for (int k = 0; k < 7; ++k) proc(b[k], (24 + k) * TPB + tid);
    }
    // tail: k=31 covers tid < 256 (NF4 = 31*1024 + 256)
    if (tid < 256) {
        const int idx = 31 * TPB + tid;
        proc(rp4[idx], idx);
    }
    __syncthreads();

    int cnt = s_cnt;
    float lo = T0;

    // ---- exact fallback: full-row NHIST histogram re-threshold (proven) ----
    if (cnt < TOPK_ || cnt > CAP) {
        for (int i = tid; i < NHIST; i += TPB) s_hist[i] = 0u;
        __syncthreads();
        for (int i = tid; i < NF4; i += TPB) {
            float4 v = rp4[i];
            float xs[4] = {v.x, v.y, v.z, v.w};
            #pragma unroll
            for (int c = 0; c < 4; ++c) {
                int b = (int)(xs[c] * (float)NHIST);
                b = min(max(b, 0), NHIST - 1);
                atomicAdd(&s_hist[b], 1u);
            }
        }
        __syncthreads();
        if (tid == 0) {
            for (int j = 0; j < T_; ++j) {    // remove unique target columns
                int id = s_ids[j];
                bool dup = false;
                for (int q = 0; q < j; ++q) dup = dup || (s_ids[q] == id);
                if (!dup) {
                    int b = (int)(rp[id] * (float)NHIST);
                    b = min(max(b, 0), NHIST - 1);
                    s_hist[b]--;
                }
            }
            int acc = 0, b = NHIST - 1;
            for (; b >= 0; --b) {
                acc += (int)s_hist[b];
                if (acc >= TOPK_) break;
            }
            s_bstar = max(b, 0);
            s_cnt = 0;
        }
        __syncthreads();
        const int bstar = s_bstar;
        lo = (float)bstar / (float)NHIST;
        for (int i = tid; i < NF4; i += TPB) {
            float4 v = rp4[i];
            int col = i << 2;
            float xs[4] = {v.x, v.y, v.z, v.w};
            #pragma unroll
            for (int c = 0; c < 4; ++c) {
                float x = xs[c];
                int b = (int)(x * (float)NHIST);
                b = min(max(b, 0), NHIST - 1);
                if (b >= bstar) {
                    int cc = col + c;
                    bool is_t = false;
                    #pragma unroll
                    for (int j = 0; j < T_; ++j) is_t |= (cc == s_ids[j]);
                    if (!is_t) {
                        int k = atomicAdd(&s_cnt, 1);
                        if (k < CAP) s_cand[k] = x;
                    }
                }
            }
        }
        __syncthreads();
        cnt = min(s_cnt, CAP);
    }

    // ---- exact top-100 sum via NB-bin histogram selection over [lo, 1) ----
    const float scale = (float)NB / (1.0f - lo);

    for (int i = tid; i < NB; i += TPB) s_hist[i] = 0u;
    __syncthreads();

    for (int i = tid; i < cnt; i += TPB) {
        int b = (int)((s_cand[i] - lo) * scale);
        b = min(max(b, 0), NB - 1);
        atomicAdd(&s_hist[b], 1u);
    }
    __syncthreads();

    if (tid < NB / 4) {                        // 4-bin chunk sums
        int base = tid << 2;
        s_chunk[tid] = s_hist[base] + s_hist[base + 1] +
                       s_hist[base + 2] + s_hist[base + 3];
    }
    __syncthreads();

    if (tid == 0) {                            // serial suffix walk (~50 chunks)
        int above = 0, bstar = 0;
        for (int c = (NB >> 2) - 1; c >= 0; --c) {
            int s = (int)s_chunk[c];
            if (above + s >= TOPK_) {
                for (int b = (c << 2) + 3; b >= (c << 2); --b) {
                    int cb = (int)s_hist[b];
                    if (above + cb >= TOPK_) { bstar = b; break; }
                    above += cb;
                }
                s_bstar = bstar;
                s_above = above;
                break;
            }
            above += s;
        }
    }
    __syncthreads();

    const int b2 = s_bstar;
    float local = 0.f;
    for (int i = tid; i < cnt; i += TPB) {
        float v = s_cand[i];
        int b = (int)((v - lo) * scale);
        b = min(max(b, 0), NB - 1);
        if (b > b2) {
            local += v;
        } else if (b == b2) {
            int k = atomicAdd(&s_bq, 1);
            if (k < BINCAP) s_bin[k] = v;
        }
    }
    #pragma unroll
    for (int off = 32; off > 0; off >>= 1) local += __shfl_down(local, off);
    if ((tid & 63) == 0) s_wred[tid >> 6] = local;
    __syncthreads();

    if (tid == 0) {
        float sum = 0.f;
        #pragma unroll
        for (int w = 0; w < 16; ++w) sum += s_wred[w];
        int q = s_bq;
        int m = TOPK_ - s_above;               // 1 <= m <= hist[b2]
        if (q <= BINCAP) {
            for (int t = 0; t < m; ++t) {
                float bv = -1e30f; int bi = 0;
                for (int i = 0; i < q; ++i)
                    if (s_bin[i] > bv) { bv = s_bin[i]; bi = i; }
                sum += bv; s_bin[bi] = -1e30f;
            }
        } else {
            // in-bin overflow (never for this data): exact serial top-100
            sum = 0.f;
            for (int t = 0; t < TOPK_; ++t) {
                float bv = -1e30f; int bi = 0;
                for (int i = 0; i < cnt; ++i)
                    if (s_cand[i] > bv) { bv = s_cand[i]; bi = i; }
                sum += bv; s_cand[bi] = -1e30f;
            }
        }
        atomicAdd(out + 2, sum * (1.0f / (B_ * TOPK_)));
    }
}

extern "C" void kernel_launch(void* const* d_in, const int* in_sizes, int n_in,
                              void* d_out, int out_size, void* d_ws, size_t ws_size,
                              hipStream_t stream) {
    const float* sparse = (const float*)d_in[0];
    const int*   tids   = (const int*)d_in[1];
    float*       out    = (float*)d_out;

    zero_out_kernel<<<1, 1, 0, stream>>>(out);
    row_kernel<<<B_, TPB, 0, stream>>>(sparse, tids, out);
}

// Round 6
// 197.671 us; speedup vs baseline: 1.0254x; 1.0254x over previous
//
#include <hip/hip_runtime.h>
#include <cstddef>
#include <cstdint>

// Problem constants (fixed by reference file)
#define B_    256
#define V_    128000
#define T_    16
#define TOPK_ 100
#define TPB   1024
#define CAP   4096
#define NF4   (V_ / 4)      // 32000 float4 per row
#define NHIST 4096          // fallback histogram bins over [0,1)
#define NB    1024          // selection histogram bins over [lo,1)
#define BINCAP 256          // in-bin candidate cap for exact tie handling
#define T0    0.996f        // speculative threshold (~512 candidates/row expected)

__global__ void zero_out_kernel(float* o) {
    o[0] = 0.f; o[1] = 0.f; o[2] = 0.f;
}

// ---------------------------------------------------------------------------
// One block per row (256 blocks x 1024 threads, 1 block/CU, 16 waves).
// Scan: depth-4 rotate register pipeline (a[4]/b[4]): while group g is
// processed, group g+1's 4 loads are in flight; group g+2 is then issued.
// Peak live = 8 float4 = 32 data VGPRs -> stays under the 128-VGPR cliff
// that spilled round-5's depth-8 version (TPB=1024 => 16 waves must fit
// => <=128 VGPR/wave).
// Select: exact top-100 sum via 1024-bin histogram; cutoff found by a
// wave-parallel suffix scan (6 shfl steps + ~8 LDS reads) instead of a
// ~54-step serial walk. Exact in-bin tie handling; proven full-row NHIST
// fallback if speculation fails. No workspace, no fences.
// ---------------------------------------------------------------------------
__global__ __launch_bounds__(TPB) void row_kernel(
        const float* __restrict__ sparse,
        const int*   __restrict__ tids,
        float*       __restrict__ out) {
    __shared__ float    s_cand[CAP];        // 16 KB
    __shared__ unsigned s_hist[NHIST];      // 16 KB (fallback all, select first NB)
    __shared__ unsigned s_chunk[NB / 4];    // 1 KB (4-bin chunk sums)
    __shared__ float    s_bin[BINCAP];      // 1 KB
    __shared__ float    s_wred[16];
    __shared__ int      s_ids[T_];
    __shared__ int      s_cnt, s_bq, s_bstar, s_above;

    const int row = blockIdx.x;
    const int tid = threadIdx.x;
    const float* __restrict__ rp = sparse + (size_t)row * V_;

    if (tid < T_) s_ids[tid] = tids[row * T_ + tid];
    if (tid == 0) { s_cnt = 0; s_bq = 0; }
    __syncthreads();

    // ---- target loss + margin loss (lanes 0..15 of wave 0) ----
    if (tid < T_) {
        float x  = rp[s_ids[tid]];
        float tl = -logf(x + 1e-8f);
        float ml = fmaxf(1.0f - x, 0.0f);
        #pragma unroll
        for (int off = 8; off > 0; off >>= 1) {
            tl += __shfl_down(tl, off);
            ml += __shfl_down(ml, off);
        }
        if (tid == 0) {
            atomicAdd(out + 0, tl * (1.0f / (B_ * T_)));
            atomicAdd(out + 1, ml * (1.0f / (B_ * T_)));
        }
    }

    const float4* __restrict__ rp4 = (const float4*)rp;

    auto proc = [&](float4 v, int i4) {
        float mx = fmaxf(fmaxf(v.x, v.y), fmaxf(v.z, v.w));
        if (mx >= T0) {                       // taken ~1.6% of the time
            int col = i4 << 2;
            float xs[4] = {v.x, v.y, v.z, v.w};
            #pragma unroll
            for (int c = 0; c < 4; ++c) {
                float x = xs[c];
                if (x >= T0) {
                    int cc = col + c;
                    bool is_t = false;
                    #pragma unroll
                    for (int j = 0; j < T_; ++j) is_t |= (cc == s_ids[j]);
                    if (!is_t) {
                        int k = atomicAdd(&s_cnt, 1);
                        if (k < CAP) s_cand[k] = x;
                    }
                }
            }
        }
    };

    // Groups of 4 k-steps: G0..G6 full (k=0..27), G7 = 3 deep (k=28..30),
    // tail k=31 (tid < 256 only; NF4 = 31*1024 + 256).
    {
        float4 a[4], b[4];
        #pragma unroll
        for (int k = 0; k < 4; ++k) a[k] = rp4[(0 * 4 + k) * TPB + tid];   // G0
        #pragma unroll
        for (int k = 0; k < 4; ++k) b[k] = rp4[(1 * 4 + k) * TPB + tid];   // G1

        #pragma unroll
        for (int k = 0; k < 4; ++k) proc(a[k], (0 * 4 + k) * TPB + tid);   // proc G0 (G1 in flight)
        #pragma unroll
        for (int k = 0; k < 4; ++k) a[k] = rp4[(2 * 4 + k) * TPB + tid];   // load G2

        #pragma unroll
        for (int k = 0; k < 4; ++k) proc(b[k], (1 * 4 + k) * TPB + tid);   // proc G1 (G2 in flight)
        #pragma unroll
        for (int k = 0; k < 4; ++k) b[k] = rp4[(3 * 4 + k) * TPB + tid];   // load G3

        #pragma unroll
        for (int k = 0; k < 4; ++k) proc(a[k], (2 * 4 + k) * TPB + tid);
        #pragma unroll
        for (int k = 0; k < 4; ++k) a[k] = rp4[(4 * 4 + k) * TPB + tid];   // load G4

        #pragma unroll
        for (int k = 0; k < 4; ++k) proc(b[k], (3 * 4 + k) * TPB + tid);
        #pragma unroll
        for (int k = 0; k < 4; ++k) b[k] = rp4[(5 * 4 + k) * TPB + tid];   // load G5

        #pragma unroll
        for (int k = 0; k < 4; ++k) proc(a[k], (4 * 4 + k) * TPB + tid);
        #pragma unroll
        for (int k = 0; k < 4; ++k) a[k] = rp4[(6 * 4 + k) * TPB + tid];   // load G6

        #pragma unroll
        for (int k = 0; k < 4; ++k) proc(b[k], (5 * 4 + k) * TPB + tid);
        #pragma unroll
        for (int k = 0; k < 3; ++k) b[k] = rp4[(7 * 4 + k) * TPB + tid];   // load G7 (3 deep)

        #pragma unroll
        for (int k = 0; k < 4; ++k) proc(a[k], (6 * 4 + k) * TPB + tid);   // proc G6 (G7 in flight)
        #pragma unroll
        for (int k = 0; k < 3; ++k) proc(b[k], (7 * 4 + k) * TPB + tid);   // proc G7
    }
    if (tid < 256) {
        const int idx = 31 * TPB + tid;
        proc(rp4[idx], idx);
    }
    __syncthreads();

    int cnt = s_cnt;
    float lo = T0;

    // ---- exact fallback: full-row NHIST histogram re-threshold (proven) ----
    if (cnt < TOPK_ || cnt > CAP) {
        for (int i = tid; i < NHIST; i += TPB) s_hist[i] = 0u;
        __syncthreads();
        for (int i = tid; i < NF4; i += TPB) {
            float4 v = rp4[i];
            float xs[4] = {v.x, v.y, v.z, v.w};
            #pragma unroll
            for (int c = 0; c < 4; ++c) {
                int b = (int)(xs[c] * (float)NHIST);
                b = min(max(b, 0), NHIST - 1);
                atomicAdd(&s_hist[b], 1u);
            }
        }
        __syncthreads();
        if (tid == 0) {
            for (int j = 0; j < T_; ++j) {    // remove unique target columns
                int id = s_ids[j];
                bool dup = false;
                for (int q = 0; q < j; ++q) dup = dup || (s_ids[q] == id);
                if (!dup) {
                    int b = (int)(rp[id] * (float)NHIST);
                    b = min(max(b, 0), NHIST - 1);
                    s_hist[b]--;
                }
            }
            int acc = 0, b = NHIST - 1;
            for (; b >= 0; --b) {
                acc += (int)s_hist[b];
                if (acc >= TOPK_) break;
            }
            s_bstar = max(b, 0);
            s_cnt = 0;
        }
        __syncthreads();
        const int bstar = s_bstar;
        lo = (float)bstar / (float)NHIST;
        for (int i = tid; i < NF4; i += TPB) {
            float4 v = rp4[i];
            int col = i << 2;
            float xs[4] = {v.x, v.y, v.z, v.w};
            #pragma unroll
            for (int c = 0; c < 4; ++c) {
                float x = xs[c];
                int b = (int)(x * (float)NHIST);
                b = min(max(b, 0), NHIST - 1);
                if (b >= bstar) {
                    int cc = col + c;
                    bool is_t = false;
                    #pragma unroll
                    for (int j = 0; j < T_; ++j) is_t |= (cc == s_ids[j]);
                    if (!is_t) {
                        int k = atomicAdd(&s_cnt, 1);
                        if (k < CAP) s_cand[k] = x;
                    }
                }
            }
        }
        __syncthreads();
        cnt = min(s_cnt, CAP);
    }

    // ---- exact top-100 sum via NB-bin histogram selection over [lo, 1) ----
    const float scale = (float)NB / (1.0f - lo);

    for (int i = tid; i < NB; i += TPB) s_hist[i] = 0u;
    __syncthreads();

    for (int i = tid; i < cnt; i += TPB) {
        int b = (int)((s_cand[i] - lo) * scale);
        b = min(max(b, 0), NB - 1);
        atomicAdd(&s_hist[b], 1u);
    }
    __syncthreads();

    if (tid < NB / 4) {                        // 4-bin chunk sums (256 chunks)
        int base = tid << 2;
        s_chunk[tid] = s_hist[base] + s_hist[base + 1] +
                       s_hist[base + 2] + s_hist[base + 3];
    }
    __syncthreads();

    // ---- wave-parallel cutoff: lane l owns chunks 4l..4l+3 (16 bins) ----
    if (tid < 64) {
        const int cb0 = tid << 2;              // first chunk of this lane
        int w = (int)(s_chunk[cb0] + s_chunk[cb0 + 1] +
                      s_chunk[cb0 + 2] + s_chunk[cb0 + 3]);
        int S = w;                             // inclusive suffix over lanes
        #pragma unroll
        for (int off = 1; off < 64; off <<= 1) {
            int t = __shfl_down(S, off);
            if (tid + off < 64) S += t;
        }
        // exactly one lane: suffix >= TOPK and strictly-above < TOPK
        if (S >= TOPK_ && (S - w) < TOPK_) {
            int above = S - w;                 // count in chunks > my range
            int bstar = cb0 << 2;
            for (int c = cb0 + 3; c >= cb0; --c) {
                int cc = (int)s_chunk[c];
                if (above + cc >= TOPK_) {     // cutoff bin inside chunk c
                    for (int b = (c << 2) + 3; b >= (c << 2); --b) {
                        int hb = (int)s_hist[b];
                        if (above + hb >= TOPK_) { bstar = b; break; }
                        above += hb;
                    }
                    break;
                }
                above += cc;
            }
            s_bstar = bstar;
            s_above = above;
        }
    }
    __syncthreads();

    const int b2 = s_bstar;
    float local = 0.f;
    for (int i = tid; i < cnt; i += TPB) {
        float v = s_cand[i];
        int b = (int)((v - lo) * scale);
        b = min(max(b, 0), NB - 1);
        if (b > b2) {
            local += v;
        } else if (b == b2) {
            int k = atomicAdd(&s_bq, 1);
            if (k < BINCAP) s_bin[k] = v;
        }
    }
    #pragma unroll
    for (int off = 32; off > 0; off >>= 1) local += __shfl_down(local, off);
    if ((tid & 63) == 0) s_wred[tid >> 6] = local;
    __syncthreads();

    if (tid == 0) {
        float sum = 0.f;
        #pragma unroll
        for (int w = 0; w < 16; ++w) sum += s_wred[w];
        int q = s_bq;
        int m = TOPK_ - s_above;               // 1 <= m <= hist[b2]
        if (q <= BINCAP) {
            for (int t = 0; t < m; ++t) {
                float bv = -1e30f; int bi = 0;
                for (int i = 0; i < q; ++i)
                    if (s_bin[i] > bv) { bv = s_bin[i]; bi = i; }
                sum += bv; s_bin[bi] = -1e30f;
            }
        } else {
            // in-bin overflow (never for this data): exact serial top-100
            sum = 0.f;
            for (int t = 0; t < TOPK_; ++t) {
                float bv = -1e30f; int bi = 0;
                for (int i = 0; i < cnt; ++i)
                    if (s_cand[i] > bv) { bv = s_cand[i]; bi = i; }
                sum += bv; s_cand[bi] = -1e30f;
            }
        }
        atomicAdd(out + 2, sum * (1.0f / (B_ * TOPK_)));
    }
}

extern "C" void kernel_launch(void* const* d_in, const int* in_sizes, int n_in,
                              void* d_out, int out_size, void* d_ws, size_t ws_size,
                              hipStream_t stream) {
    const float* sparse = (const float*)d_in[0];
    const int*   tids   = (const int*)d_in[1];
    float*       out    = (float*)d_out;

    zero_out_kernel<<<1, 1, 0, stream>>>(out);
    row_kernel<<<B_, TPB, 0, stream>>>(sparse, tids, out);
}

// Round 7
// 189.215 us; speedup vs baseline: 1.0712x; 1.0447x over previous
//
#include <hip/hip_runtime.h>
#include <cstddef>
#include <cstdint>

// Problem constants (fixed by reference file)
#define B_    256
#define V_    128000
#define T_    16
#define TOPK_ 100
#define TPB   1024
#define CAP   4096
#define NF4   (V_ / 4)      // 32000 float4 per row
#define NHIST 4096          // fallback histogram bins over [0,1)
#define NB    1024          // selection histogram bins over [lo,1)
#define BINCAP 256          // in-bin candidate cap for exact tie handling
#define T0    0.996f        // speculative threshold (~512 candidates/row expected)

typedef float f32x4 __attribute__((ext_vector_type(4)));

__global__ void zero_out_kernel(float* o) {
    o[0] = 0.f; o[1] = 0.f; o[2] = 0.f;
}

// ---------------------------------------------------------------------------
// One block per row (256 blocks x 1024 threads, 1 block/CU, 16 waves).
// Scan (r4-proven grouped depth-4 ILP batches, now with non-temporal loads):
// candidates >= T0 are appended to s_cand AND binned into the selection
// histogram inline (fused: the tail's histogram pass + barrier is gone).
// Tail: wave-parallel cutoff search, one sweep for sum + cutoff-bin collect,
// exact in-bin tie handling. Proven full-row NHIST fallback if speculation
// fails (rebuilds its own selection histogram). No workspace, no fences.
// VGPR budget: 8 live f32x4 = 32 data VGPRs, well under the 128/wave cliff
// (TPB=1024 -> 16 waves/CU must co-reside).
// ---------------------------------------------------------------------------
__global__ __launch_bounds__(TPB) void row_kernel(
        const float* __restrict__ sparse,
        const int*   __restrict__ tids,
        float*       __restrict__ out) {
    __shared__ float    s_cand[CAP];        // 16 KB
    __shared__ unsigned s_hist[NHIST];      // 16 KB (select: first NB; fallback: all)
    __shared__ unsigned s_chunk[NB / 4];    // 1 KB (4-bin chunk sums)
    __shared__ float    s_bin[BINCAP];      // 1 KB
    __shared__ float    s_wred[16];
    __shared__ int      s_ids[T_];
    __shared__ int      s_cnt, s_bq, s_bstar, s_above;

    const int row = blockIdx.x;
    const int tid = threadIdx.x;
    const float* __restrict__ rp = sparse + (size_t)row * V_;

    const float scale0 = (float)NB / (1.0f - T0);

    if (tid < T_) s_ids[tid] = tids[row * T_ + tid];
    if (tid == 0) { s_cnt = 0; s_bq = 0; }
    for (int i = tid; i < NB; i += TPB) s_hist[i] = 0u;   // scan-time bins
    __syncthreads();

    // ---- target loss + margin loss (lanes 0..15 of wave 0) ----
    if (tid < T_) {
        float x  = rp[s_ids[tid]];
        float tl = -logf(x + 1e-8f);
        float ml = fmaxf(1.0f - x, 0.0f);
        #pragma unroll
        for (int off = 8; off > 0; off >>= 1) {
            tl += __shfl_down(tl, off);
            ml += __shfl_down(ml, off);
        }
        if (tid == 0) {
            atomicAdd(out + 0, tl * (1.0f / (B_ * T_)));
            atomicAdd(out + 1, ml * (1.0f / (B_ * T_)));
        }
    }

    const f32x4* __restrict__ rp4 = (const f32x4*)rp;

    // accept: append to s_cand AND bin into the selection histogram (fused)
    auto proc = [&](f32x4 v, int i4) {
        float mx = fmaxf(fmaxf(v.x, v.y), fmaxf(v.z, v.w));
        if (mx >= T0) {                       // taken ~1.6% of the time
            int col = i4 << 2;
            float xs[4] = {v.x, v.y, v.z, v.w};
            #pragma unroll
            for (int c = 0; c < 4; ++c) {
                float x = xs[c];
                if (x >= T0) {
                    int cc = col + c;
                    bool is_t = false;
                    #pragma unroll
                    for (int j = 0; j < T_; ++j) is_t |= (cc == s_ids[j]);
                    if (!is_t) {
                        int k = atomicAdd(&s_cnt, 1);
                        if (k < CAP) s_cand[k] = x;
                        int b = (int)((x - T0) * scale0);   // >= 0 since x >= T0
                        b = min(b, NB - 1);
                        atomicAdd(&s_hist[b], 1u);
                    }
                }
            }
        }
    };

    // r4-proven grouped depth-4 batches; NF4 = 7*(4*1024) + 3*1024 + 256
    #pragma unroll
    for (int g = 0; g < 7; ++g) {
        const int base = g * 4 * TPB + tid;
        f32x4 va = __builtin_nontemporal_load(&rp4[base]);
        f32x4 vb = __builtin_nontemporal_load(&rp4[base + TPB]);
        f32x4 vc = __builtin_nontemporal_load(&rp4[base + 2 * TPB]);
        f32x4 vd = __builtin_nontemporal_load(&rp4[base + 3 * TPB]);
        proc(va, base);
        proc(vb, base + TPB);
        proc(vc, base + 2 * TPB);
        proc(vd, base + 3 * TPB);
    }
    {
        const int base = 28 * TPB + tid;
        f32x4 va = __builtin_nontemporal_load(&rp4[base]);
        f32x4 vb = __builtin_nontemporal_load(&rp4[base + TPB]);
        f32x4 vc = __builtin_nontemporal_load(&rp4[base + 2 * TPB]);
        proc(va, base);
        proc(vb, base + TPB);
        proc(vc, base + 2 * TPB);
    }
    if (tid < 256) {
        const int idx = 31 * TPB + tid;       // 31744 + tid -> 32000
        f32x4 v = __builtin_nontemporal_load(&rp4[idx]);
        proc(v, idx);
    }
    __syncthreads();

    int cnt = s_cnt;
    float lo = T0;
    float scale = scale0;

    // ---- exact fallback: full-row NHIST histogram re-threshold (proven) ----
    if (cnt < TOPK_ || cnt > CAP) {
        for (int i = tid; i < NHIST; i += TPB) s_hist[i] = 0u;
        __syncthreads();
        for (int i = tid; i < NF4; i += TPB) {
            f32x4 v = rp4[i];
            float xs[4] = {v.x, v.y, v.z, v.w};
            #pragma unroll
            for (int c = 0; c < 4; ++c) {
                int b = (int)(xs[c] * (float)NHIST);
                b = min(max(b, 0), NHIST - 1);
                atomicAdd(&s_hist[b], 1u);
            }
        }
        __syncthreads();
        if (tid == 0) {
            for (int j = 0; j < T_; ++j) {    // remove unique target columns
                int id = s_ids[j];
                bool dup = false;
                for (int q = 0; q < j; ++q) dup = dup || (s_ids[q] == id);
                if (!dup) {
                    int b = (int)(rp[id] * (float)NHIST);
                    b = min(max(b, 0), NHIST - 1);
                    s_hist[b]--;
                }
            }
            int acc = 0, b = NHIST - 1;
            for (; b >= 0; --b) {
                acc += (int)s_hist[b];
                if (acc >= TOPK_) break;
            }
            s_bstar = max(b, 0);
            s_cnt = 0;
        }
        __syncthreads();
        const int bstar = s_bstar;
        lo = (float)bstar / (float)NHIST;
        scale = (float)NB / (1.0f - lo);
        for (int i = tid; i < NF4; i += TPB) {
            f32x4 v = rp4[i];
            int col = i << 2;
            float xs[4] = {v.x, v.y, v.z, v.w};
            #pragma unroll
            for (int c = 0; c < 4; ++c) {
                float x = xs[c];
                int b = (int)(x * (float)NHIST);
                b = min(max(b, 0), NHIST - 1);
                if (b >= bstar) {
                    int cc = col + c;
                    bool is_t = false;
                    #pragma unroll
                    for (int j = 0; j < T_; ++j) is_t |= (cc == s_ids[j]);
                    if (!is_t) {
                        int k = atomicAdd(&s_cnt, 1);
                        if (k < CAP) s_cand[k] = x;
                    }
                }
            }
        }
        __syncthreads();
        cnt = min(s_cnt, CAP);

        // rebuild the NB selection histogram over [lo, 1) for collected cands
        for (int i = tid; i < NB; i += TPB) s_hist[i] = 0u;
        __syncthreads();
        for (int i = tid; i < cnt; i += TPB) {
            int b = (int)((s_cand[i] - lo) * scale);
            b = min(max(b, 0), NB - 1);
            atomicAdd(&s_hist[b], 1u);
        }
        __syncthreads();
    }

    // ---- exact top-100 sum from the (already-built) NB-bin histogram ----
    if (tid < NB / 4) {                        // 4-bin chunk sums (256 chunks)
        int base = tid << 2;
        s_chunk[tid] = s_hist[base] + s_hist[base + 1] +
                       s_hist[base + 2] + s_hist[base + 3];
    }
    __syncthreads();

    // wave-parallel cutoff: lane l owns chunks 4l..4l+3 (16 bins)
    if (tid < 64) {
        const int cb0 = tid << 2;
        int w = (int)(s_chunk[cb0] + s_chunk[cb0 + 1] +
                      s_chunk[cb0 + 2] + s_chunk[cb0 + 3]);
        int S = w;                             // inclusive suffix over lanes
        #pragma unroll
        for (int off = 1; off < 64; off <<= 1) {
            int t = __shfl_down(S, off);
            if (tid + off < 64) S += t;
        }
        if (S >= TOPK_ && (S - w) < TOPK_) {   // exactly one lane matches
            int above = S - w;
            int bstar = cb0 << 2;
            for (int c = cb0 + 3; c >= cb0; --c) {
                int cc = (int)s_chunk[c];
                if (above + cc >= TOPK_) {
                    for (int b = (c << 2) + 3; b >= (c << 2); --b) {
                        int hb = (int)s_hist[b];
                        if (above + hb >= TOPK_) { bstar = b; break; }
                        above += hb;
                    }
                    break;
                }
                above += cc;
            }
            s_bstar = bstar;
            s_above = above;
        }
    }
    __syncthreads();

    const int b2 = s_bstar;
    float local = 0.f;
    for (int i = tid; i < cnt; i += TPB) {
        float v = s_cand[i];
        int b = (int)((v - lo) * scale);
        b = min(max(b, 0), NB - 1);
        if (b > b2) {
            local += v;
        } else if (b == b2) {
            int k = atomicAdd(&s_bq, 1);
            if (k < BINCAP) s_bin[k] = v;
        }
    }
    #pragma unroll
    for (int off = 32; off > 0; off >>= 1) local += __shfl_down(local, off);
    if ((tid & 63) == 0) s_wred[tid >> 6] = local;
    __syncthreads();

    if (tid == 0) {
        float sum = 0.f;
        #pragma unroll
        for (int w = 0; w < 16; ++w) sum += s_wred[w];
        int q = s_bq;
        int m = TOPK_ - s_above;               // 1 <= m <= hist[b2]
        if (q <= BINCAP) {
            for (int t = 0; t < m; ++t) {
                float bv = -1e30f; int bi = 0;
                for (int i = 0; i < q; ++i)
                    if (s_bin[i] > bv) { bv = s_bin[i]; bi = i; }
                sum += bv; s_bin[bi] = -1e30f;
            }
        } else {
            // in-bin overflow (never for this data): exact serial top-100
            sum = 0.f;
            for (int t = 0; t < TOPK_; ++t) {
                float bv = -1e30f; int bi = 0;
                for (int i = 0; i < cnt; ++i)
                    if (s_cand[i] > bv) { bv = s_cand[i]; bi = i; }
                sum += bv; s_cand[bi] = -1e30f;
            }
        }
        atomicAdd(out + 2, sum * (1.0f / (B_ * TOPK_)));
    }
}

extern "C" void kernel_launch(void* const* d_in, const int* in_sizes, int n_in,
                              void* d_out, int out_size, void* d_ws, size_t ws_size,
                              hipStream_t stream) {
    const float* sparse = (const float*)d_in[0];
    const int*   tids   = (const int*)d_in[1];
    float*       out    = (float*)d_out;

    zero_out_kernel<<<1, 1, 0, stream>>>(out);
    row_kernel<<<B_, TPB, 0, stream>>>(sparse, tids, out);
}